// Round 2
// baseline (136.503 us; speedup 1.0000x reference)
//
#include <hip/hip_runtime.h>

#define N2 16384
#define N1 65536
#define N0 262144

// ---- output layout (float offsets) ----
#define OUT_AIM 7225344         // 21*21*N2
#define OUT_LD  14450688        // 2*21*21*N2
#define OUT_ZRE 14450689
#define OUT_ZIM 14794753        // OUT_ZRE + 21*N2

// Fully fused: each block (blockIdx.x = j-chunk, blockIdx.y = output row p)
// recomputes the cheap stage-0/1 Schur quantities it needs in registers
// (redundantly across the 21 p-rows; inputs are L2/L3-resident), builds all
// 20 T2 values per column j in registers, then emits its output row + zout.
__global__ __launch_bounds__(256) void fused_kernel(
    const float* __restrict__ l00r, const float* __restrict__ l00i,
    const float* __restrict__ l01r, const float* __restrict__ l01i,
    const float* __restrict__ l02r, const float* __restrict__ l02i,
    const float* __restrict__ l11r, const float* __restrict__ l11i,
    const float* __restrict__ l12r, const float* __restrict__ l12i,
    const float* __restrict__ l22r, const float* __restrict__ l22i,
    const float* __restrict__ zre,  const float* __restrict__ zim,
    float* __restrict__ out, double* __restrict__ ld_partial)
{
    const int j   = blockIdx.x * 256 + threadIdx.x;
    const int p   = blockIdx.y;
    const int a_p = p >> 2, u_p = p & 3;

    float t2r[20], t2i[20];
    float m2tr = 0.f, m2ti = 0.f;     // M2 = sum_q conj(B2[q]) * T2[q]
    float ld = 0.f;
    // stashed A1 terms for the scatter (valid for u == u_p)
    float st1r[4], st1i[4], sp1r[4], sp1i[4];
    float si0r = 0.f, si0i = 0.f, ss1r = 0.f, ss1i = 0.f;

#pragma unroll
    for (int u = 0; u < 4; ++u) {
        const int m = u * N2 + j;
        // ---- stage 0/1: inv00, T1 = lam01/lam00, S1, P1 = T1/S1 ----
        float i0r[4], i0i[4], t1r[4], t1i[4], p1r[4], p1i[4];
        float m1r = 0.f, m1i = 0.f;
#pragma unroll
        for (int k = 0; k < 4; ++k) {
            const int i = k * N1 + m;
            const float ar = l00r[i], ai = l00i[i];
            const float br = l01r[i], bi = l01i[i];
            const float d  = ar*ar + ai*ai;
            const float rd = 1.f / d;
            ld += 0.5f * logf(d);                   // log|lam00|
            const float xr = ar * rd, xi = -ai * rd;
            i0r[k] = xr; i0i[k] = xi;
            const float tr = br*xr - bi*xi;
            const float ti = br*xi + bi*xr;
            t1r[k] = tr; t1i[k] = ti;
            m1r += br*tr + bi*ti;                   // conj(lam01)*T1
            m1i += br*ti - bi*tr;
        }
        const float s1r = l11r[m] - m1r;
        const float s1i = l11i[m] - m1i;
        const float ds1 = s1r*s1r + s1i*s1i;
        ld += 0.5f * logf(ds1);                     // log|S1|
        const float rds1 = 1.f / ds1;
        const float is1r = s1r * rds1, is1i = -s1i * rds1;
#pragma unroll
        for (int k = 0; k < 4; ++k) {
            p1r[k] = t1r[k]*is1r - t1i[k]*is1i;
            p1i[k] = t1r[k]*is1i + t1i[k]*is1r;
        }

        // ---- stage-2 B column at m: Bcol[a<4]=lam02[a*N1+m], Bcol[4]=lam12[m]
        float bcr[5], bci[5];
#pragma unroll
        for (int a = 0; a < 4; ++a) { bcr[a] = l02r[a*N1+m]; bci[a] = l02i[a*N1+m]; }
        bcr[4] = l12r[m]; bci[4] = l12i[m];

        // W = sum_{b<4} Bcol[b]*conj(T1[b]) - Bcol[4]
        float wr = -bcr[4], wi = -bci[4];
#pragma unroll
        for (int b = 0; b < 4; ++b) {
            wr += bcr[b]*t1r[b] + bci[b]*t1i[b];
            wi += bci[b]*t1r[b] - bcr[b]*t1i[b];
        }
        // T2[a*4+u]: a<4: P1[a]*W + Bcol[a]*inv00[a]; a=4: Bcol[4]/S1 - sum Bcol[b]*conj(P1[b])
        float ur[5], ui[5];
#pragma unroll
        for (int a = 0; a < 4; ++a) {
            ur[a] = p1r[a]*wr - p1i[a]*wi + bcr[a]*i0r[a] - bci[a]*i0i[a];
            ui[a] = p1r[a]*wi + p1i[a]*wr + bcr[a]*i0i[a] + bci[a]*i0r[a];
        }
        {
            float vr = bcr[4]*is1r - bci[4]*is1i;
            float vi = bcr[4]*is1i + bci[4]*is1r;
#pragma unroll
            for (int b = 0; b < 4; ++b) {
                vr -= bcr[b]*p1r[b] + bci[b]*p1i[b];
                vi -= bci[b]*p1r[b] - bcr[b]*p1i[b];
            }
            ur[4] = vr; ui[4] = vi;
        }
#pragma unroll
        for (int a = 0; a < 5; ++a) {
            t2r[a*4 + u] = ur[a];
            t2i[a*4 + u] = ui[a];
            m2tr += bcr[a]*ur[a] + bci[a]*ui[a];
            m2ti += bcr[a]*ui[a] - bci[a]*ur[a];
        }
        if (u == u_p) {
#pragma unroll
            for (int b = 0; b < 4; ++b) {
                st1r[b] = t1r[b]; st1i[b] = t1i[b];
                sp1r[b] = p1r[b]; sp1i[b] = p1i[b];
            }
            si0r = i0r[a_p & 3]; si0i = i0i[a_p & 3];
            ss1r = is1r;         ss1i = is1i;
        }
    }

    // ---- S2 and its inverse ----
    const float s2r = l22r[j] - m2tr;
    const float s2i = l22i[j] - m2ti;
    const float ds2  = s2r*s2r + s2i*s2i;
    const float rds2 = 1.f / ds2;
    const float is2r = s2r * rds2, is2i = -s2i * rds2;
    ld += 0.5f * logf(ds2);                          // log|S2|

    // ---- emit output row p ----
    float zar = 0.f, zai = 0.f;
    if (p == 20) {
#pragma unroll
        for (int q = 0; q < 21; ++q) {
            float ar, ai;
            if (q < 20) {
                const float pr = t2r[q]*is2r - t2i[q]*is2i;   // P2[q]
                const float pi = t2r[q]*is2i + t2i[q]*is2r;
                ar = -pr; ai = pi;                            // -conj(P2[q])
            } else { ar = is2r; ai = is2i; }
            out[(p*21 + q)*N2 + j]           = ar;
            out[OUT_AIM + (p*21 + q)*N2 + j] = ai;
            const float zqr = zre[q*N2 + j], zqi = zim[q*N2 + j];
            zar += zqr*ar - zqi*ai;
            zai += zqr*ai + zqi*ar;
        }
    } else {
        const float ppr = t2r[p]*is2r - t2i[p]*is2i;          // P2[p]
        const float ppi = t2r[p]*is2i + t2i[p]*is2r;
#pragma unroll
        for (int q = 0; q < 21; ++q) {
            float ar, ai;
            if (q < 20) {
                ar = ppr*t2r[q] + ppi*t2i[q];                 // P2[p]*conj(T2[q])
                ai = ppi*t2r[q] - ppr*t2i[q];
                if ((q & 3) == u_p) {                         // + A1[a_p][q>>2]
                    const int b = q >> 2;
                    if (a_p < 4) {
                        if (b < 4) {
                            ar += sp1r[a_p]*st1r[b] + sp1i[a_p]*st1i[b];
                            ai += sp1i[a_p]*st1r[b] - sp1r[a_p]*st1i[b];
                            if (b == a_p) { ar += si0r; ai += si0i; }
                        } else { ar -= sp1r[a_p]; ai -= sp1i[a_p]; }
                    } else {
                        if (b < 4) { ar -= sp1r[b]; ai += sp1i[b]; }  // -conj(P1[b])
                        else       { ar += ss1r; ai += ss1i; }        // 1/S1
                    }
                }
            } else { ar = -ppr; ai = -ppi; }                  // -P2[p]
            out[(p*21 + q)*N2 + j]           = ar;
            out[OUT_AIM + (p*21 + q)*N2 + j] = ai;
            const float zqr = zre[q*N2 + j], zqi = zim[q*N2 + j];
            zar += zqr*ar - zqi*ai;
            zai += zqr*ai + zqi*ar;
        }
    }
    out[OUT_ZRE + p*N2 + j] = zar;
    out[OUT_ZIM + p*N2 + j] = zai;

    // ---- logdet partial (only the p==0 row contributes; covers all of
    //      lam00 (k,u span N0), S1 (u spans N1), S2 exactly once) ----
    if (p == 0) {
        float v = ld;
#pragma unroll
        for (int off = 32; off > 0; off >>= 1) v += __shfl_down(v, off, 64);
        __shared__ float wsum[4];
        const int lane = threadIdx.x & 63;
        const int wid  = threadIdx.x >> 6;
        if (lane == 0) wsum[wid] = v;
        __syncthreads();
        if (threadIdx.x == 0)
            ld_partial[blockIdx.x] =
                (double)wsum[0] + (double)wsum[1] + (double)wsum[2] + (double)wsum[3];
    }
}

__global__ void finalize_kernel(const double* __restrict__ part,
                                float* __restrict__ out) {
    double v = part[threadIdx.x];                    // 64 partials, one wave
#pragma unroll
    for (int off = 32; off > 0; off >>= 1) v += __shfl_down(v, off, 64);
    if (threadIdx.x == 0) out[OUT_LD] = (float)v;
}

extern "C" void kernel_launch(void* const* d_in, const int* in_sizes, int n_in,
                              void* d_out, int out_size, void* d_ws, size_t ws_size,
                              hipStream_t stream)
{
    const float* l00r = (const float*)d_in[0];
    const float* l00i = (const float*)d_in[1];
    const float* l01r = (const float*)d_in[2];
    const float* l01i = (const float*)d_in[3];
    const float* l02r = (const float*)d_in[4];
    const float* l02i = (const float*)d_in[5];
    const float* l11r = (const float*)d_in[6];
    const float* l11i = (const float*)d_in[7];
    const float* l12r = (const float*)d_in[8];
    const float* l12i = (const float*)d_in[9];
    const float* l22r = (const float*)d_in[10];
    const float* l22i = (const float*)d_in[11];
    const float* zre  = (const float*)d_in[12];
    const float* zim  = (const float*)d_in[13];
    float*  out        = (float*)d_out;
    double* ld_partial = (double*)d_ws;              // 64 doubles, written before read

    fused_kernel<<<dim3(N2/256, 21), dim3(256), 0, stream>>>(
        l00r,l00i,l01r,l01i,l02r,l02i,l11r,l11i,l12r,l12i,l22r,l22i,
        zre,zim, out, ld_partial);
    finalize_kernel<<<1, 64, 0, stream>>>(ld_partial, out);
}

// Round 3
// 112.398 us; speedup vs baseline: 1.2145x; 1.2145x over previous
//
#include <hip/hip_runtime.h>

#define N2 16384
#define N1 65536

// ---- output layout (float offsets) ----
#define OUT_AIM 7225344         // 21*21*N2
#define OUT_LD  14450688        // 2*21*21*N2
#define OUT_ZRE 14450689
#define OUT_ZIM 14794753        // OUT_ZRE + 21*N2

// ---- LDS layout (float offsets), TILE_J = 64 ----
#define L_T2R  0                // [20][64]
#define L_T2I  1280
#define L_M2   2560             // [c:2][u:4][64]
#define L_SC   3072             // [idx:26][u:4][64]
//   idx 0..3  t1r[b], 4..7  t1i[b], 8..11 p1r[b], 12..15 p1i[b],
//   idx 16..19 i0r[k], 20..23 i0i[k], 24 is1r, 25 is1i
#define L_IS2R 9728             // [64]
#define L_IS2I 9792
#define L_RED  9856             // [8]
#define L_TOT  9864             // 38.5 KB

#define SC(idx, u, jl) lds[L_SC + (((idx)*4 + (u)) * 64) + (jl)]

// grid = N2/64 blocks of 512 threads. Phase 1: threads (u,jl) compute the
// stage-0/1/2 Schur chain once per column into LDS. Phase 2: 8 wave-groups
// emit all 21 output rows (A row-blocks + zout) for the 64 columns.
__global__ __launch_bounds__(512) void fused_kernel(
    const float* __restrict__ l00r, const float* __restrict__ l00i,
    const float* __restrict__ l01r, const float* __restrict__ l01i,
    const float* __restrict__ l02r, const float* __restrict__ l02i,
    const float* __restrict__ l11r, const float* __restrict__ l11i,
    const float* __restrict__ l12r, const float* __restrict__ l12i,
    const float* __restrict__ l22r, const float* __restrict__ l22i,
    const float* __restrict__ zre,  const float* __restrict__ zim,
    float* __restrict__ out, double* __restrict__ ld_partial)
{
    __shared__ float lds[L_TOT];
    const int t  = threadIdx.x;
    const int jl = t & 63;
    const int j0 = blockIdx.x * 64;
    float ld = 0.f;

    // ================= phase 1: stage 0/1/2 per (u, jl) =================
    if (t < 256) {
        const int u = t >> 6;
        const int m = u * N2 + (j0 + jl);

        float i0r[4], i0i[4], t1r[4], t1i[4], p1r[4], p1i[4];
        float m1r = 0.f, m1i = 0.f;
#pragma unroll
        for (int k = 0; k < 4; ++k) {
            const int i = k * N1 + m;
            const float ar = l00r[i], ai = l00i[i];
            const float br = l01r[i], bi = l01i[i];
            const float d  = ar*ar + ai*ai;
            const float rd = 1.f / d;
            ld += 0.5f * logf(d);                   // log|lam00|
            const float xr = ar * rd, xi = -ai * rd;
            i0r[k] = xr; i0i[k] = xi;
            const float tr = br*xr - bi*xi;         // T1 = lam01/lam00
            const float ti = br*xi + bi*xr;
            t1r[k] = tr; t1i[k] = ti;
            m1r += br*tr + bi*ti;                   // conj(lam01)*T1
            m1i += br*ti - bi*tr;
        }
        const float s1r = l11r[m] - m1r;
        const float s1i = l11i[m] - m1i;
        const float ds1 = s1r*s1r + s1i*s1i;
        ld += 0.5f * logf(ds1);                     // log|S1|
        const float rds1 = 1.f / ds1;
        const float is1r = s1r * rds1, is1i = -s1i * rds1;
#pragma unroll
        for (int k = 0; k < 4; ++k) {
            p1r[k] = t1r[k]*is1r - t1i[k]*is1i;     // P1 = T1/S1
            p1i[k] = t1r[k]*is1i + t1i[k]*is1r;
        }

        // stage-2 B column: Bcol[a<4]=lam02[a*N1+m], Bcol[4]=lam12[m]
        float bcr[5], bci[5];
#pragma unroll
        for (int a = 0; a < 4; ++a) { bcr[a] = l02r[a*N1+m]; bci[a] = l02i[a*N1+m]; }
        bcr[4] = l12r[m]; bci[4] = l12i[m];

        // W = sum_{b<4} Bcol[b]*conj(T1[b]) - Bcol[4]
        float wr = -bcr[4], wi = -bci[4];
#pragma unroll
        for (int b = 0; b < 4; ++b) {
            wr += bcr[b]*t1r[b] + bci[b]*t1i[b];
            wi += bci[b]*t1r[b] - bcr[b]*t1i[b];
        }
        // T2 rows q = a*4+u
        float ur[5], ui[5];
#pragma unroll
        for (int a = 0; a < 4; ++a) {
            ur[a] = p1r[a]*wr - p1i[a]*wi + bcr[a]*i0r[a] - bci[a]*i0i[a];
            ui[a] = p1r[a]*wi + p1i[a]*wr + bcr[a]*i0i[a] + bci[a]*i0r[a];
        }
        {
            float vr = bcr[4]*is1r - bci[4]*is1i;   // Bcol[4]/S1
            float vi = bcr[4]*is1i + bci[4]*is1r;
#pragma unroll
            for (int b = 0; b < 4; ++b) {           // - Bcol[b]*conj(P1[b])
                vr -= bcr[b]*p1r[b] + bci[b]*p1i[b];
                vi -= bci[b]*p1r[b] - bcr[b]*p1i[b];
            }
            ur[4] = vr; ui[4] = vi;
        }
        float m2r = 0.f, m2i = 0.f;
#pragma unroll
        for (int a = 0; a < 5; ++a) {
            lds[L_T2R + (a*4+u)*64 + jl] = ur[a];
            lds[L_T2I + (a*4+u)*64 + jl] = ui[a];
            m2r += bcr[a]*ur[a] + bci[a]*ui[a];     // conj(B)*T2
            m2i += bcr[a]*ui[a] - bci[a]*ur[a];
        }
        lds[L_M2 + (0*4+u)*64 + jl] = m2r;
        lds[L_M2 + (1*4+u)*64 + jl] = m2i;
#pragma unroll
        for (int b = 0; b < 4; ++b) {
            SC(b,      u, jl) = t1r[b];  SC(4+b,  u, jl) = t1i[b];
            SC(8+b,    u, jl) = p1r[b];  SC(12+b, u, jl) = p1i[b];
            SC(16+b,   u, jl) = i0r[b];  SC(20+b, u, jl) = i0i[b];
        }
        SC(24, u, jl) = is1r;  SC(25, u, jl) = is1i;
    }
    __syncthreads();

    // ================= phase 1.5: S2 per column =================
    if (t < 64) {
        float s2r = l22r[j0 + t], s2i = l22i[j0 + t];
#pragma unroll
        for (int u = 0; u < 4; ++u) {
            s2r -= lds[L_M2 + (0*4+u)*64 + t];
            s2i -= lds[L_M2 + (1*4+u)*64 + t];
        }
        const float ds2  = s2r*s2r + s2i*s2i;
        const float rds2 = 1.f / ds2;
        lds[L_IS2R + t] =  s2r * rds2;
        lds[L_IS2I + t] = -s2i * rds2;
        ld += 0.5f * logf(ds2);                     // log|S2|
    }
    __syncthreads();

    // ================= phase 2: emit rows =================
    const int g = t >> 6;                           // wave group 0..7
    const int j = j0 + jl;
    const float is2r = lds[L_IS2R + jl];
    const float is2i = lds[L_IS2I + jl];

    float zr[21], zi[21];
#pragma unroll
    for (int q = 0; q < 21; ++q) { zr[q] = zre[q*N2+j]; zi[q] = zim[q*N2+j]; }

    for (int p = g; p < 21; p += 8) {
        float zar = 0.f, zai = 0.f;
        if (p == 20) {
#pragma unroll
            for (int q = 0; q < 21; ++q) {
                float ar, ai;
                if (q < 20) {
                    const float tqr = lds[L_T2R + q*64 + jl];
                    const float tqi = lds[L_T2I + q*64 + jl];
                    ar = -(tqr*is2r - tqi*is2i);    // -conj(P2[q])
                    ai =  (tqr*is2i + tqi*is2r);
                } else { ar = is2r; ai = is2i; }
                out[(p*21 + q)*N2 + j]           = ar;
                out[OUT_AIM + (p*21 + q)*N2 + j] = ai;
                zar += zr[q]*ar - zi[q]*ai;
                zai += zr[q]*ai + zi[q]*ar;
            }
        } else {
            const int a_p = p >> 2, u_p = p & 3;
            const float tpr = lds[L_T2R + p*64 + jl];
            const float tpi = lds[L_T2I + p*64 + jl];
            const float ppr = tpr*is2r - tpi*is2i;  // P2[p]
            const float ppi = tpr*is2i + tpi*is2r;
            // scatter addends for q = b*4 + u_p
            float sar[5], sai[5];
            if (a_p < 4) {
                const float par = SC(8+a_p, u_p, jl), pai = SC(12+a_p, u_p, jl);
#pragma unroll
                for (int b = 0; b < 4; ++b) {
                    const float tbr = SC(b, u_p, jl), tbi = SC(4+b, u_p, jl);
                    sar[b] = par*tbr + pai*tbi;     // P1[a]*conj(T1[b])
                    sai[b] = pai*tbr - par*tbi;
                }
                sar[a_p] += SC(16+a_p, u_p, jl);    // + 1/lam00
                sai[a_p] += SC(20+a_p, u_p, jl);
                sar[4] = -par; sai[4] = -pai;       // -P1[a]
            } else {
#pragma unroll
                for (int b = 0; b < 4; ++b) {       // -conj(P1[b])
                    sar[b] = -SC(8+b,  u_p, jl);
                    sai[b] =  SC(12+b, u_p, jl);
                }
                sar[4] = SC(24, u_p, jl);           // 1/S1
                sai[4] = SC(25, u_p, jl);
            }
#pragma unroll
            for (int q = 0; q < 21; ++q) {
                float ar, ai;
                if (q < 20) {
                    const float tqr = lds[L_T2R + q*64 + jl];
                    const float tqi = lds[L_T2I + q*64 + jl];
                    ar = ppr*tqr + ppi*tqi;         // P2[p]*conj(T2[q])
                    ai = ppi*tqr - ppr*tqi;
                    if ((q & 3) == u_p) { ar += sar[q>>2]; ai += sai[q>>2]; }
                } else { ar = -ppr; ai = -ppi; }    // -P2[p]
                out[(p*21 + q)*N2 + j]           = ar;
                out[OUT_AIM + (p*21 + q)*N2 + j] = ai;
                zar += zr[q]*ar - zi[q]*ai;
                zai += zr[q]*ai + zi[q]*ar;
            }
        }
        out[OUT_ZRE + p*N2 + j] = zar;
        out[OUT_ZIM + p*N2 + j] = zai;
    }

    // ================= logdet block reduction =================
    float v = ld;
#pragma unroll
    for (int off = 32; off > 0; off >>= 1) v += __shfl_down(v, off, 64);
    __syncthreads();                                // LDS reuse guard
    if (jl == 0) lds[L_RED + g] = v;
    __syncthreads();
    if (t == 0) {
        double s = 0.0;
#pragma unroll
        for (int w = 0; w < 8; ++w) s += (double)lds[L_RED + w];
        ld_partial[blockIdx.x] = s;
    }
}

__global__ void finalize_kernel(const double* __restrict__ part,
                                float* __restrict__ out) {
    double v = part[threadIdx.x];                   // 256 partials
#pragma unroll
    for (int off = 32; off > 0; off >>= 1) v += __shfl_down(v, off, 64);
    __shared__ double wsum[4];
    if ((threadIdx.x & 63) == 0) wsum[threadIdx.x >> 6] = v;
    __syncthreads();
    if (threadIdx.x == 0)
        out[OUT_LD] = (float)(wsum[0] + wsum[1] + wsum[2] + wsum[3]);
}

extern "C" void kernel_launch(void* const* d_in, const int* in_sizes, int n_in,
                              void* d_out, int out_size, void* d_ws, size_t ws_size,
                              hipStream_t stream)
{
    const float* l00r = (const float*)d_in[0];
    const float* l00i = (const float*)d_in[1];
    const float* l01r = (const float*)d_in[2];
    const float* l01i = (const float*)d_in[3];
    const float* l02r = (const float*)d_in[4];
    const float* l02i = (const float*)d_in[5];
    const float* l11r = (const float*)d_in[6];
    const float* l11i = (const float*)d_in[7];
    const float* l12r = (const float*)d_in[8];
    const float* l12i = (const float*)d_in[9];
    const float* l22r = (const float*)d_in[10];
    const float* l22i = (const float*)d_in[11];
    const float* zre  = (const float*)d_in[12];
    const float* zim  = (const float*)d_in[13];
    float*  out        = (float*)d_out;
    double* ld_partial = (double*)d_ws;             // 256 doubles, written each call

    fused_kernel<<<dim3(N2/64), dim3(512), 0, stream>>>(
        l00r,l00i,l01r,l01i,l02r,l02i,l11r,l11i,l12r,l12i,l22r,l22i,
        zre,zim, out, ld_partial);
    finalize_kernel<<<1, 256, 0, stream>>>(ld_partial, out);
}

// Round 4
// 111.691 us; speedup vs baseline: 1.2221x; 1.0063x over previous
//
#include <hip/hip_runtime.h>

#define N2 16384
#define N1 65536

// ---- output layout (float offsets) ----
#define OUT_AIM 7225344         // 21*21*N2
#define OUT_LD  14450688        // 2*21*21*N2
#define OUT_ZRE 14450689
#define OUT_ZIM 14794753        // OUT_ZRE + 21*N2

// ---- LDS layout (float offsets), TILE_J = 64 ----
#define L_T2R  0                // [20][64]
#define L_T2I  1280
#define L_M2   2560             // [c:2][u:4][64]
#define L_SC   3072             // [idx:26][u:4][64]
//   idx 0..3  t1r[b], 4..7  t1i[b], 8..11 p1r[b], 12..15 p1i[b],
//   idx 16..19 i0r[k], 20..23 i0i[k], 24 is1r, 25 is1i
#define L_IS2R 9728             // [64]
#define L_IS2I 9792
#define L_RED  9856             // [7]
#define L_TOT  9864             // 38.5 KB

#define SC(idx, u, jl) lds[L_SC + (((idx)*4 + (u)) * 64) + (jl)]

// grid = (N2/64, 3), block = 448 threads (7 waves).
// Phase 1 (t<256): stage-0/1/2 Schur chain per (u, jl) into LDS (redundant
// across the 3 y-slices; inputs are L2/L3-resident; logf only in y==0).
// Phase 2: wave-group g emits output row p = y*7 + g for 64 columns.
__global__ __launch_bounds__(448) void fused_kernel(
    const float* __restrict__ l00r, const float* __restrict__ l00i,
    const float* __restrict__ l01r, const float* __restrict__ l01i,
    const float* __restrict__ l02r, const float* __restrict__ l02i,
    const float* __restrict__ l11r, const float* __restrict__ l11i,
    const float* __restrict__ l12r, const float* __restrict__ l12i,
    const float* __restrict__ l22r, const float* __restrict__ l22i,
    const float* __restrict__ zre,  const float* __restrict__ zim,
    float* __restrict__ out, double* __restrict__ ld_partial)
{
    __shared__ float lds[L_TOT];
    const int t   = threadIdx.x;
    const int jl  = t & 63;
    const int j0  = blockIdx.x * 64;
    const bool y0 = (blockIdx.y == 0);
    float ld = 0.f;

    // ================= phase 1: stage 0/1/2 per (u, jl) =================
    if (t < 256) {
        const int u = t >> 6;
        const int m = u * N2 + (j0 + jl);

        float i0r[4], i0i[4], t1r[4], t1i[4], p1r[4], p1i[4];
        float m1r = 0.f, m1i = 0.f;
#pragma unroll
        for (int k = 0; k < 4; ++k) {
            const int i = k * N1 + m;
            const float ar = l00r[i], ai = l00i[i];
            const float br = l01r[i], bi = l01i[i];
            const float d  = ar*ar + ai*ai;
            const float rd = 1.f / d;
            if (y0) ld += 0.5f * logf(d);           // log|lam00|
            const float xr = ar * rd, xi = -ai * rd;
            i0r[k] = xr; i0i[k] = xi;
            const float tr = br*xr - bi*xi;         // T1 = lam01/lam00
            const float ti = br*xi + bi*xr;
            t1r[k] = tr; t1i[k] = ti;
            m1r += br*tr + bi*ti;                   // conj(lam01)*T1
            m1i += br*ti - bi*tr;
        }
        const float s1r = l11r[m] - m1r;
        const float s1i = l11i[m] - m1i;
        const float ds1 = s1r*s1r + s1i*s1i;
        if (y0) ld += 0.5f * logf(ds1);             // log|S1|
        const float rds1 = 1.f / ds1;
        const float is1r = s1r * rds1, is1i = -s1i * rds1;
#pragma unroll
        for (int k = 0; k < 4; ++k) {
            p1r[k] = t1r[k]*is1r - t1i[k]*is1i;     // P1 = T1/S1
            p1i[k] = t1r[k]*is1i + t1i[k]*is1r;
        }

        // stage-2 B column: Bcol[a<4]=lam02[a*N1+m], Bcol[4]=lam12[m]
        float bcr[5], bci[5];
#pragma unroll
        for (int a = 0; a < 4; ++a) { bcr[a] = l02r[a*N1+m]; bci[a] = l02i[a*N1+m]; }
        bcr[4] = l12r[m]; bci[4] = l12i[m];

        // W = sum_{b<4} Bcol[b]*conj(T1[b]) - Bcol[4]
        float wr = -bcr[4], wi = -bci[4];
#pragma unroll
        for (int b = 0; b < 4; ++b) {
            wr += bcr[b]*t1r[b] + bci[b]*t1i[b];
            wi += bci[b]*t1r[b] - bcr[b]*t1i[b];
        }
        // T2 rows q = a*4+u
        float ur[5], ui[5];
#pragma unroll
        for (int a = 0; a < 4; ++a) {
            ur[a] = p1r[a]*wr - p1i[a]*wi + bcr[a]*i0r[a] - bci[a]*i0i[a];
            ui[a] = p1r[a]*wi + p1i[a]*wr + bcr[a]*i0i[a] + bci[a]*i0r[a];
        }
        {
            float vr = bcr[4]*is1r - bci[4]*is1i;   // Bcol[4]/S1
            float vi = bcr[4]*is1i + bci[4]*is1r;
#pragma unroll
            for (int b = 0; b < 4; ++b) {           // - Bcol[b]*conj(P1[b])
                vr -= bcr[b]*p1r[b] + bci[b]*p1i[b];
                vi -= bci[b]*p1r[b] - bcr[b]*p1i[b];
            }
            ur[4] = vr; ui[4] = vi;
        }
        float m2r = 0.f, m2i = 0.f;
#pragma unroll
        for (int a = 0; a < 5; ++a) {
            lds[L_T2R + (a*4+u)*64 + jl] = ur[a];
            lds[L_T2I + (a*4+u)*64 + jl] = ui[a];
            m2r += bcr[a]*ur[a] + bci[a]*ui[a];     // conj(B)*T2
            m2i += bcr[a]*ui[a] - bci[a]*ur[a];
        }
        lds[L_M2 + (0*4+u)*64 + jl] = m2r;
        lds[L_M2 + (1*4+u)*64 + jl] = m2i;
#pragma unroll
        for (int b = 0; b < 4; ++b) {
            SC(b,      u, jl) = t1r[b];  SC(4+b,  u, jl) = t1i[b];
            SC(8+b,    u, jl) = p1r[b];  SC(12+b, u, jl) = p1i[b];
            SC(16+b,   u, jl) = i0r[b];  SC(20+b, u, jl) = i0i[b];
        }
        SC(24, u, jl) = is1r;  SC(25, u, jl) = is1i;
    }
    __syncthreads();

    // ================= phase 1.5: S2 per column =================
    if (t < 64) {
        float s2r = l22r[j0 + t], s2i = l22i[j0 + t];
#pragma unroll
        for (int u = 0; u < 4; ++u) {
            s2r -= lds[L_M2 + (0*4+u)*64 + t];
            s2i -= lds[L_M2 + (1*4+u)*64 + t];
        }
        const float ds2  = s2r*s2r + s2i*s2i;
        const float rds2 = 1.f / ds2;
        lds[L_IS2R + t] =  s2r * rds2;
        lds[L_IS2I + t] = -s2i * rds2;
        if (y0) ld += 0.5f * logf(ds2);             // log|S2|
    }
    __syncthreads();

    // ================= phase 2: emit one row per wave-group =================
    const int g = t >> 6;                           // wave group 0..6
    const int p = blockIdx.y * 7 + g;               // output row 0..20
    const int j = j0 + jl;
    const float is2r = lds[L_IS2R + jl];
    const float is2i = lds[L_IS2I + jl];

    float zr[21], zi[21];
#pragma unroll
    for (int q = 0; q < 21; ++q) { zr[q] = zre[q*N2+j]; zi[q] = zim[q*N2+j]; }

    float zar = 0.f, zai = 0.f;
    if (p == 20) {
#pragma unroll
        for (int q = 0; q < 21; ++q) {
            float ar, ai;
            if (q < 20) {
                const float tqr = lds[L_T2R + q*64 + jl];
                const float tqi = lds[L_T2I + q*64 + jl];
                ar = -(tqr*is2r - tqi*is2i);        // -conj(P2[q])
                ai =  (tqr*is2i + tqi*is2r);
            } else { ar = is2r; ai = is2i; }
            out[(p*21 + q)*N2 + j]           = ar;
            out[OUT_AIM + (p*21 + q)*N2 + j] = ai;
            zar += zr[q]*ar - zi[q]*ai;
            zai += zr[q]*ai + zi[q]*ar;
        }
    } else {
        const int a_p = p >> 2, u_p = p & 3;
        const float tpr = lds[L_T2R + p*64 + jl];
        const float tpi = lds[L_T2I + p*64 + jl];
        const float ppr = tpr*is2r - tpi*is2i;      // P2[p]
        const float ppi = tpr*is2i + tpi*is2r;
        // scatter addends for q = b*4 + u_p
        float sar[5], sai[5];
        if (a_p < 4) {
            const float par = SC(8+a_p, u_p, jl), pai = SC(12+a_p, u_p, jl);
#pragma unroll
            for (int b = 0; b < 4; ++b) {
                const float tbr = SC(b, u_p, jl), tbi = SC(4+b, u_p, jl);
                sar[b] = par*tbr + pai*tbi;         // P1[a]*conj(T1[b])
                sai[b] = pai*tbr - par*tbi;
            }
            sar[a_p] += SC(16+a_p, u_p, jl);        // + 1/lam00
            sai[a_p] += SC(20+a_p, u_p, jl);
            sar[4] = -par; sai[4] = -pai;           // -P1[a]
        } else {
#pragma unroll
            for (int b = 0; b < 4; ++b) {           // -conj(P1[b])
                sar[b] = -SC(8+b,  u_p, jl);
                sai[b] =  SC(12+b, u_p, jl);
            }
            sar[4] = SC(24, u_p, jl);               // 1/S1
            sai[4] = SC(25, u_p, jl);
        }
#pragma unroll
        for (int q = 0; q < 21; ++q) {
            float ar, ai;
            if (q < 20) {
                const float tqr = lds[L_T2R + q*64 + jl];
                const float tqi = lds[L_T2I + q*64 + jl];
                ar = ppr*tqr + ppi*tqi;             // P2[p]*conj(T2[q])
                ai = ppi*tqr - ppr*tqi;
                if ((q & 3) == u_p) { ar += sar[q>>2]; ai += sai[q>>2]; }
            } else { ar = -ppr; ai = -ppi; }        // -P2[p]
            out[(p*21 + q)*N2 + j]           = ar;
            out[OUT_AIM + (p*21 + q)*N2 + j] = ai;
            zar += zr[q]*ar - zi[q]*ai;
            zai += zr[q]*ai + zi[q]*ar;
        }
    }
    out[OUT_ZRE + p*N2 + j] = zar;
    out[OUT_ZIM + p*N2 + j] = zai;

    // ================= logdet block reduction (y==0 only) =================
    if (y0) {
        float v = ld;
#pragma unroll
        for (int off = 32; off > 0; off >>= 1) v += __shfl_down(v, off, 64);
        __syncthreads();                            // LDS reuse guard
        if (jl == 0) lds[L_RED + g] = v;
        __syncthreads();
        if (t == 0) {
            double s = 0.0;
#pragma unroll
            for (int w = 0; w < 7; ++w) s += (double)lds[L_RED + w];
            ld_partial[blockIdx.x] = s;
        }
    }
}

__global__ void finalize_kernel(const double* __restrict__ part,
                                float* __restrict__ out) {
    double v = part[threadIdx.x];                   // 256 partials
#pragma unroll
    for (int off = 32; off > 0; off >>= 1) v += __shfl_down(v, off, 64);
    __shared__ double wsum[4];
    if ((threadIdx.x & 63) == 0) wsum[threadIdx.x >> 6] = v;
    __syncthreads();
    if (threadIdx.x == 0)
        out[OUT_LD] = (float)(wsum[0] + wsum[1] + wsum[2] + wsum[3]);
}

extern "C" void kernel_launch(void* const* d_in, const int* in_sizes, int n_in,
                              void* d_out, int out_size, void* d_ws, size_t ws_size,
                              hipStream_t stream)
{
    const float* l00r = (const float*)d_in[0];
    const float* l00i = (const float*)d_in[1];
    const float* l01r = (const float*)d_in[2];
    const float* l01i = (const float*)d_in[3];
    const float* l02r = (const float*)d_in[4];
    const float* l02i = (const float*)d_in[5];
    const float* l11r = (const float*)d_in[6];
    const float* l11i = (const float*)d_in[7];
    const float* l12r = (const float*)d_in[8];
    const float* l12i = (const float*)d_in[9];
    const float* l22r = (const float*)d_in[10];
    const float* l22i = (const float*)d_in[11];
    const float* zre  = (const float*)d_in[12];
    const float* zim  = (const float*)d_in[13];
    float*  out        = (float*)d_out;
    double* ld_partial = (double*)d_ws;             // 256 doubles, written each call

    fused_kernel<<<dim3(N2/64, 3), dim3(448), 0, stream>>>(
        l00r,l00i,l01r,l01i,l02r,l02i,l11r,l11i,l12r,l12i,l22r,l22i,
        zre,zim, out, ld_partial);
    finalize_kernel<<<1, 256, 0, stream>>>(ld_partial, out);
}

// Round 5
// 111.292 us; speedup vs baseline: 1.2265x; 1.0036x over previous
//
#include <hip/hip_runtime.h>

#define N2 16384
#define N1 65536

// ---- output layout (float offsets) ----
#define OUT_AIM 7225344         // 21*21*N2
#define OUT_LD  14450688        // 2*21*21*N2
#define OUT_ZRE 14450689
#define OUT_ZIM 14794753        // OUT_ZRE + 21*N2

// ---- LDS layout (float offsets), TILE_J = 64 ----
#define L_T2R  0                // [20][64]
#define L_T2I  1280
#define L_M2   2560             // [c:2][u:4][64]
#define L_SC   3072             // [idx:26][u:4][64]
//   idx 0..3  t1r[b], 4..7  t1i[b], 8..11 p1r[b], 12..15 p1i[b],
//   idx 16..19 i0r[k], 20..23 i0i[k], 24 is1r, 25 is1i
#define L_IS2R 9728             // [64]
#define L_IS2I 9792
#define L_RED  9856             // [7]
#define L_TOT  9864             // 38.5 KB

#define SC(idx, u, jl) lds[L_SC + (((idx)*4 + (u)) * 64) + (jl)]

// packed 8-byte non-temporal store of two adjacent floats
#define NTST2(addr, v0, v1) do {                                   \
    union { float f[2]; long L; } _u; _u.f[0] = (v0); _u.f[1] = (v1); \
    __builtin_nontemporal_store(_u.L, (long*)(addr)); } while (0)

// grid = (N2/64, 3), block = 448 threads (7 waves).
// Phase 1 (t<256): stage-0/1/2 Schur chain per (u, jl) into LDS (redundant
// across the 3 y-slices; inputs are L2/L3-resident; logf only in y==0).
// Phase 2: wave-group g emits output row p = y*7 + g; lane owns 2 adjacent
// columns, half-wave owns one q-parity -> packed dwordx2 NT stores.
__global__ __launch_bounds__(448) void fused_kernel(
    const float* __restrict__ l00r, const float* __restrict__ l00i,
    const float* __restrict__ l01r, const float* __restrict__ l01i,
    const float* __restrict__ l02r, const float* __restrict__ l02i,
    const float* __restrict__ l11r, const float* __restrict__ l11i,
    const float* __restrict__ l12r, const float* __restrict__ l12i,
    const float* __restrict__ l22r, const float* __restrict__ l22i,
    const float* __restrict__ zre,  const float* __restrict__ zim,
    float* __restrict__ out, double* __restrict__ ld_partial)
{
    __shared__ float lds[L_TOT];
    const int t   = threadIdx.x;
    const int jl  = t & 63;
    const int j0  = blockIdx.x * 64;
    const bool y0 = (blockIdx.y == 0);
    float ld = 0.f;

    // ================= phase 1: stage 0/1/2 per (u, jl) =================
    if (t < 256) {
        const int u = t >> 6;
        const int m = u * N2 + (j0 + jl);

        float i0r[4], i0i[4], t1r[4], t1i[4], p1r[4], p1i[4];
        float m1r = 0.f, m1i = 0.f;
#pragma unroll
        for (int k = 0; k < 4; ++k) {
            const int i = k * N1 + m;
            const float ar = l00r[i], ai = l00i[i];
            const float br = l01r[i], bi = l01i[i];
            const float d  = ar*ar + ai*ai;
            const float rd = 1.f / d;
            if (y0) ld += 0.5f * logf(d);           // log|lam00|
            const float xr = ar * rd, xi = -ai * rd;
            i0r[k] = xr; i0i[k] = xi;
            const float tr = br*xr - bi*xi;         // T1 = lam01/lam00
            const float ti = br*xi + bi*xr;
            t1r[k] = tr; t1i[k] = ti;
            m1r += br*tr + bi*ti;                   // conj(lam01)*T1
            m1i += br*ti - bi*tr;
        }
        const float s1r = l11r[m] - m1r;
        const float s1i = l11i[m] - m1i;
        const float ds1 = s1r*s1r + s1i*s1i;
        if (y0) ld += 0.5f * logf(ds1);             // log|S1|
        const float rds1 = 1.f / ds1;
        const float is1r = s1r * rds1, is1i = -s1i * rds1;
#pragma unroll
        for (int k = 0; k < 4; ++k) {
            p1r[k] = t1r[k]*is1r - t1i[k]*is1i;     // P1 = T1/S1
            p1i[k] = t1r[k]*is1i + t1i[k]*is1r;
        }

        // stage-2 B column: Bcol[a<4]=lam02[a*N1+m], Bcol[4]=lam12[m]
        float bcr[5], bci[5];
#pragma unroll
        for (int a = 0; a < 4; ++a) { bcr[a] = l02r[a*N1+m]; bci[a] = l02i[a*N1+m]; }
        bcr[4] = l12r[m]; bci[4] = l12i[m];

        // W = sum_{b<4} Bcol[b]*conj(T1[b]) - Bcol[4]
        float wr = -bcr[4], wi = -bci[4];
#pragma unroll
        for (int b = 0; b < 4; ++b) {
            wr += bcr[b]*t1r[b] + bci[b]*t1i[b];
            wi += bci[b]*t1r[b] - bcr[b]*t1i[b];
        }
        // T2 rows q = a*4+u
        float ur[5], ui[5];
#pragma unroll
        for (int a = 0; a < 4; ++a) {
            ur[a] = p1r[a]*wr - p1i[a]*wi + bcr[a]*i0r[a] - bci[a]*i0i[a];
            ui[a] = p1r[a]*wi + p1i[a]*wr + bcr[a]*i0i[a] + bci[a]*i0r[a];
        }
        {
            float vr = bcr[4]*is1r - bci[4]*is1i;   // Bcol[4]/S1
            float vi = bcr[4]*is1i + bci[4]*is1r;
#pragma unroll
            for (int b = 0; b < 4; ++b) {           // - Bcol[b]*conj(P1[b])
                vr -= bcr[b]*p1r[b] + bci[b]*p1i[b];
                vi -= bci[b]*p1r[b] - bcr[b]*p1i[b];
            }
            ur[4] = vr; ui[4] = vi;
        }
        float m2r = 0.f, m2i = 0.f;
#pragma unroll
        for (int a = 0; a < 5; ++a) {
            lds[L_T2R + (a*4+u)*64 + jl] = ur[a];
            lds[L_T2I + (a*4+u)*64 + jl] = ui[a];
            m2r += bcr[a]*ur[a] + bci[a]*ui[a];     // conj(B)*T2
            m2i += bcr[a]*ui[a] - bci[a]*ur[a];
        }
        lds[L_M2 + (0*4+u)*64 + jl] = m2r;
        lds[L_M2 + (1*4+u)*64 + jl] = m2i;
#pragma unroll
        for (int b = 0; b < 4; ++b) {
            SC(b,      u, jl) = t1r[b];  SC(4+b,  u, jl) = t1i[b];
            SC(8+b,    u, jl) = p1r[b];  SC(12+b, u, jl) = p1i[b];
            SC(16+b,   u, jl) = i0r[b];  SC(20+b, u, jl) = i0i[b];
        }
        SC(24, u, jl) = is1r;  SC(25, u, jl) = is1i;
    }
    __syncthreads();

    // ================= phase 1.5: S2 per column =================
    if (t < 64) {
        float s2r = l22r[j0 + t], s2i = l22i[j0 + t];
#pragma unroll
        for (int u = 0; u < 4; ++u) {
            s2r -= lds[L_M2 + (0*4+u)*64 + t];
            s2i -= lds[L_M2 + (1*4+u)*64 + t];
        }
        const float ds2  = s2r*s2r + s2i*s2i;
        const float rds2 = 1.f / ds2;
        lds[L_IS2R + t] =  s2r * rds2;
        lds[L_IS2I + t] = -s2i * rds2;
        if (y0) ld += 0.5f * logf(ds2);             // log|S2|
    }
    __syncthreads();

    // ========= phase 2: row p, lane = (h: q-parity, c: column pair) =========
    const int g  = t >> 6;                          // wave group 0..6
    const int p  = blockIdx.y * 7 + g;              // output row 0..20
    const int l  = t & 63;
    const int h  = l >> 5;                          // q parity
    const int c  = l & 31;                          // column-pair index
    const int c2 = 2*c;
    const int j2 = j0 + c2;                         // first of the 2 columns

    const float is2r0 = lds[L_IS2R + c2],   is2r1 = lds[L_IS2R + c2+1];
    const float is2i0 = lds[L_IS2I + c2],   is2i1 = lds[L_IS2I + c2+1];

    float zar0=0.f, zai0=0.f, zar1=0.f, zai1=0.f;

    if (p == 20) {
#pragma unroll
        for (int qi = 0; qi < 11; ++qi) {
            const int q = 2*qi + h;
            if (q >= 21) continue;
            float ar0, ai0, ar1, ai1;
            if (q < 20) {
                const float tr0 = lds[L_T2R + q*64 + c2], tr1 = lds[L_T2R + q*64 + c2+1];
                const float ti0 = lds[L_T2I + q*64 + c2], ti1 = lds[L_T2I + q*64 + c2+1];
                ar0 = -(tr0*is2r0 - ti0*is2i0);  ai0 = tr0*is2i0 + ti0*is2r0;
                ar1 = -(tr1*is2r1 - ti1*is2i1);  ai1 = tr1*is2i1 + ti1*is2r1;
            } else { ar0=is2r0; ai0=is2i0; ar1=is2r1; ai1=is2i1; }
            NTST2(out + (p*21+q)*N2 + j2,           ar0, ar1);
            NTST2(out + OUT_AIM + (p*21+q)*N2 + j2, ai0, ai1);
            const float zr0 = zre[q*N2+j2], zr1 = zre[q*N2+j2+1];
            const float zi0 = zim[q*N2+j2], zi1 = zim[q*N2+j2+1];
            zar0 += zr0*ar0 - zi0*ai0;  zai0 += zr0*ai0 + zi0*ar0;
            zar1 += zr1*ar1 - zi1*ai1;  zai1 += zr1*ai1 + zi1*ar1;
        }
    } else {
        const int a_p = p >> 2, u_p = p & 3;
        const float tpr0 = lds[L_T2R + p*64 + c2], tpr1 = lds[L_T2R + p*64 + c2+1];
        const float tpi0 = lds[L_T2I + p*64 + c2], tpi1 = lds[L_T2I + p*64 + c2+1];
        const float ppr0 = tpr0*is2r0 - tpi0*is2i0, ppi0 = tpr0*is2i0 + tpi0*is2r0;
        const float ppr1 = tpr1*is2r1 - tpi1*is2i1, ppi1 = tpr1*is2i1 + tpi1*is2r1;
        float par0=0.f, pai0=0.f, par1=0.f, pai1=0.f;   // P1[a_p] (rows a_p<4)
        if (a_p < 4) {
            par0 = SC(8+a_p,  u_p, c2);   pai0 = SC(12+a_p, u_p, c2);
            par1 = SC(8+a_p,  u_p, c2+1); pai1 = SC(12+a_p, u_p, c2+1);
        }
#pragma unroll
        for (int qi = 0; qi < 11; ++qi) {
            const int q = 2*qi + h;
            if (q >= 21) continue;
            float ar0, ai0, ar1, ai1;
            if (q < 20) {
                const float tr0 = lds[L_T2R + q*64 + c2], tr1 = lds[L_T2R + q*64 + c2+1];
                const float ti0 = lds[L_T2I + q*64 + c2], ti1 = lds[L_T2I + q*64 + c2+1];
                ar0 = ppr0*tr0 + ppi0*ti0;  ai0 = ppi0*tr0 - ppr0*ti0;  // P2[p]*conj(T2[q])
                ar1 = ppr1*tr1 + ppi1*ti1;  ai1 = ppi1*tr1 - ppr1*ti1;
                if ((q & 3) == u_p) {                   // + A1[a_p][q>>2] scatter
                    const int b = q >> 2;
                    if (a_p < 4) {
                        if (b < 4) {
                            const float tbr0 = SC(b, u_p, c2),   tbi0 = SC(4+b, u_p, c2);
                            const float tbr1 = SC(b, u_p, c2+1), tbi1 = SC(4+b, u_p, c2+1);
                            ar0 += par0*tbr0 + pai0*tbi0;  ai0 += pai0*tbr0 - par0*tbi0;
                            ar1 += par1*tbr1 + pai1*tbi1;  ai1 += pai1*tbr1 - par1*tbi1;
                            if (b == a_p) {                     // + 1/lam00
                                ar0 += SC(16+a_p, u_p, c2);   ai0 += SC(20+a_p, u_p, c2);
                                ar1 += SC(16+a_p, u_p, c2+1); ai1 += SC(20+a_p, u_p, c2+1);
                            }
                        } else { ar0 -= par0; ai0 -= pai0; ar1 -= par1; ai1 -= pai1; } // -P1[a]
                    } else {
                        if (b < 4) {                            // -conj(P1[b])
                            ar0 -= SC(8+b, u_p, c2);   ai0 += SC(12+b, u_p, c2);
                            ar1 -= SC(8+b, u_p, c2+1); ai1 += SC(12+b, u_p, c2+1);
                        } else {                                // 1/S1
                            ar0 += SC(24, u_p, c2);   ai0 += SC(25, u_p, c2);
                            ar1 += SC(24, u_p, c2+1); ai1 += SC(25, u_p, c2+1);
                        }
                    }
                }
            } else { ar0 = -ppr0; ai0 = -ppi0; ar1 = -ppr1; ai1 = -ppi1; } // -P2[p]
            NTST2(out + (p*21+q)*N2 + j2,           ar0, ar1);
            NTST2(out + OUT_AIM + (p*21+q)*N2 + j2, ai0, ai1);
            const float zr0 = zre[q*N2+j2], zr1 = zre[q*N2+j2+1];
            const float zi0 = zim[q*N2+j2], zi1 = zim[q*N2+j2+1];
            zar0 += zr0*ar0 - zi0*ai0;  zai0 += zr0*ai0 + zi0*ar0;
            zar1 += zr1*ar1 - zi1*ai1;  zai1 += zr1*ai1 + zi1*ar1;
        }
    }

    // combine q-parity halves, remap to 1 col/lane, coalesced NT store
    zar0 += __shfl_xor(zar0, 32, 64);  zai0 += __shfl_xor(zai0, 32, 64);
    zar1 += __shfl_xor(zar1, 32, 64);  zai1 += __shfl_xor(zai1, 32, 64);
    {
        const int src = l >> 1;
        const float e_r = __shfl(zar0, src, 64), o_r = __shfl(zar1, src, 64);
        const float e_i = __shfl(zai0, src, 64), o_i = __shfl(zai1, src, 64);
        const float zvr = (l & 1) ? o_r : e_r;
        const float zvi = (l & 1) ? o_i : e_i;
        __builtin_nontemporal_store(zvr, out + OUT_ZRE + p*N2 + j0 + l);
        __builtin_nontemporal_store(zvi, out + OUT_ZIM + p*N2 + j0 + l);
    }

    // ================= logdet block reduction (y==0 only) =================
    if (y0) {
        float v = ld;
#pragma unroll
        for (int off = 32; off > 0; off >>= 1) v += __shfl_down(v, off, 64);
        __syncthreads();                            // LDS reuse guard
        if (jl == 0) lds[L_RED + g] = v;
        __syncthreads();
        if (t == 0) {
            double s = 0.0;
#pragma unroll
            for (int w = 0; w < 7; ++w) s += (double)lds[L_RED + w];
            ld_partial[blockIdx.x] = s;
        }
    }
}

__global__ void finalize_kernel(const double* __restrict__ part,
                                float* __restrict__ out) {
    double v = part[threadIdx.x];                   // 256 partials
#pragma unroll
    for (int off = 32; off > 0; off >>= 1) v += __shfl_down(v, off, 64);
    __shared__ double wsum[4];
    if ((threadIdx.x & 63) == 0) wsum[threadIdx.x >> 6] = v;
    __syncthreads();
    if (threadIdx.x == 0)
        out[OUT_LD] = (float)(wsum[0] + wsum[1] + wsum[2] + wsum[3]);
}

extern "C" void kernel_launch(void* const* d_in, const int* in_sizes, int n_in,
                              void* d_out, int out_size, void* d_ws, size_t ws_size,
                              hipStream_t stream)
{
    const float* l00r = (const float*)d_in[0];
    const float* l00i = (const float*)d_in[1];
    const float* l01r = (const float*)d_in[2];
    const float* l01i = (const float*)d_in[3];
    const float* l02r = (const float*)d_in[4];
    const float* l02i = (const float*)d_in[5];
    const float* l11r = (const float*)d_in[6];
    const float* l11i = (const float*)d_in[7];
    const float* l12r = (const float*)d_in[8];
    const float* l12i = (const float*)d_in[9];
    const float* l22r = (const float*)d_in[10];
    const float* l22i = (const float*)d_in[11];
    const float* zre  = (const float*)d_in[12];
    const float* zim  = (const float*)d_in[13];
    float*  out        = (float*)d_out;
    double* ld_partial = (double*)d_ws;             // 256 doubles, written each call

    fused_kernel<<<dim3(N2/64, 3), dim3(448), 0, stream>>>(
        l00r,l00i,l01r,l01i,l02r,l02i,l11r,l11i,l12r,l12i,l22r,l22i,
        zre,zim, out, ld_partial);
    finalize_kernel<<<1, 256, 0, stream>>>(ld_partial, out);
}